// Round 7
// baseline (261.110 us; speedup 1.0000x reference)
//
#include <hip/hip_runtime.h>
#include <stdint.h>

typedef __attribute__((ext_vector_type(8))) short bf16x8;
typedef __attribute__((ext_vector_type(4))) float f32x4;
typedef unsigned short u16;
typedef unsigned int   u32;

#define S_LEN 2048
#define NH    16
#define NKV   4
#define DH    128
#define DM    2048
#define QKV_N 3072
#define MROWS 4096   // B*S

__device__ __forceinline__ u16 f2bf(float x) {
  u32 u = __float_as_uint(x);
  return (u16)((u + 0x7fffu + ((u >> 16) & 1u)) >> 16);   // RNE
}
__device__ __forceinline__ float bf2f(u16 h) {
  return __uint_as_float(((u32)h) << 16);
}
__device__ __forceinline__ u32 cvtpk(float lo, float hi) {   // T12: 1 instr vs ~8 VALU
  u32 r;
  asm("v_cvt_pk_bf16_f32 %0, %1, %2" : "=v"(r) : "v"(lo), "v"(hi));
  return r;
}
__device__ __forceinline__ void gload_lds16(const void* g, void* l) {
  __builtin_amdgcn_global_load_lds((const __attribute__((address_space(1))) void*)g,
                                   (__attribute__((address_space(3))) void*)l, 16, 0, 0);
}

// ---------------- f32 -> bf16 convert (vectorized, G13) ----------------
__global__ void __launch_bounds__(256) convert_x_kernel(const float* __restrict__ x,
                                                        u16* __restrict__ o) {
  int idx = (blockIdx.x * 256 + threadIdx.x) * 8;
  float4 a = *(const float4*)(x + idx);
  float4 b = *(const float4*)(x + idx + 4);
  union { u16 s[8]; uint4 v; } t;
  t.s[0] = f2bf(a.x); t.s[1] = f2bf(a.y); t.s[2] = f2bf(a.z); t.s[3] = f2bf(a.w);
  t.s[4] = f2bf(b.x); t.s[5] = f2bf(b.y); t.s[6] = f2bf(b.z); t.s[7] = f2bf(b.w);
  *(uint4*)(o + idx) = t.v;
}

// ------------- W [2048][N] f32  ->  Wt [N][2048] bf16 (LDS tiled) -------------
__global__ void __launch_bounds__(256) transpose_w_kernel(const float* __restrict__ src,
                                                          u16* __restrict__ dst, int N) {
  __shared__ float t[64][65];
  const int bx = blockIdx.x, by = blockIdx.y, tid = threadIdx.x;
#pragma unroll
  for (int rep = 0; rep < 16; ++rep) {
    int lin = rep * 256 + tid;
    int i = lin >> 6, jj = lin & 63;                 // i = k-local, jj = n-local
    t[i][jj] = src[(size_t)(bx * 64 + i) * N + by * 64 + jj];
  }
  __syncthreads();
#pragma unroll
  for (int rep = 0; rep < 16; ++rep) {
    int lin = rep * 256 + tid;
    int nr = lin >> 6, kc = lin & 63;
    dst[(size_t)(by * 64 + nr) * DM + bx * 64 + kc] = f2bf(t[kc][nr]);
  }
}

// ------------- RoPE tables: ctab/stab[s*64 + i] -------------
__global__ void __launch_bounds__(256) rope_tables_kernel(float* __restrict__ ct,
                                                          float* __restrict__ st_) {
  int idx = blockIdx.x * 256 + threadIdx.x;          // 2048*64
  int s = idx >> 6, i = idx & 63;
  const float L2_10000 = 13.287712379549449f;
  float freq = exp2f(-(float)i * (1.0f / 64.0f) * L2_10000);
  float ang = (float)s * freq;
  ct[idx] = cosf(ang);
  st_[idx] = sinf(ang);
}

// ------------- GEMM: C[M][N] = A[M][K](bf16) * Bt[N][K](bf16)^T  (m97 structure) -------------
template <int OUTF32>
__global__ void __launch_bounds__(256) gemm_bt(const u16* __restrict__ A,
                                               const u16* __restrict__ Bt,
                                               void* __restrict__ C,
                                               int M, int N, int K) {
  __shared__ __align__(16) u16 As[128 * 32];
  __shared__ __align__(16) u16 Bs[128 * 32];
  const int tid = threadIdx.x;
  const int w = tid >> 6, l = tid & 63;
  const int g = l >> 4, q15 = l & 15;
  const int row0 = blockIdx.y * 128, col0 = blockIdx.x * 128;
  const int wm = (w >> 1) * 64, wn = (w & 1) * 64;
  const f32x4 fz = {0.f, 0.f, 0.f, 0.f};
  f32x4 acc[4][4];
#pragma unroll
  for (int m = 0; m < 4; ++m)
#pragma unroll
    for (int n = 0; n < 4; ++n) acc[m][n] = fz;

  for (int kt = 0; kt < K; kt += 32) {
#pragma unroll
    for (int c = 0; c < 2; ++c) {
      int P = (w * 2 + c) * 1024;
      int Pl = P + l * 16;
      int arow = Pl >> 6, acolb = Pl & 63;          // 64B per 32-elem row
      gload_lds16((const char*)A + ((size_t)(row0 + arow) * K + kt) * 2 + acolb,
                  (char*)As + P);
      gload_lds16((const char*)Bt + ((size_t)(col0 + arow) * K + kt) * 2 + acolb,
                  (char*)Bs + P);
    }
    __syncthreads();
    bf16x8 af[4], bfv[4];
#pragma unroll
    for (int m = 0; m < 4; ++m)
      af[m] = *(const bf16x8*)((const char*)As + (wm + m * 16 + q15) * 64 + g * 16);
#pragma unroll
    for (int n = 0; n < 4; ++n)
      bfv[n] = *(const bf16x8*)((const char*)Bs + (wn + n * 16 + q15) * 64 + g * 16);
#pragma unroll
    for (int m = 0; m < 4; ++m)
#pragma unroll
      for (int n = 0; n < 4; ++n)
        acc[m][n] = __builtin_amdgcn_mfma_f32_16x16x32_bf16(af[m], bfv[n], acc[m][n], 0, 0, 0);
    __syncthreads();
  }
#pragma unroll
  for (int m = 0; m < 4; ++m)
#pragma unroll
    for (int n = 0; n < 4; ++n)
#pragma unroll
      for (int r = 0; r < 4; ++r) {
        int rr = row0 + wm + m * 16 + g * 4 + r;    // C/D: row=(l>>4)*4+reg
        int cc = col0 + wn + n * 16 + q15;          //      col=l&15
        float v = acc[m][n][r];
        if (OUTF32) ((float*)C)[(size_t)rr * N + cc] = v;
        else        ((u16*)C)[(size_t)rr * N + cc]  = f2bf(v);
      }
}

// ------------- fused RMSNorm + RoPE; one wave per (row, head-job) -------------
// jobs 0..15 = q heads (pre-scaled by 1/sqrt(DH)), 16..19 = k heads
__global__ void __launch_bounds__(256) norm_rope_kernel(const u16* __restrict__ qkv,
                                                        const float* __restrict__ qw,
                                                        const float* __restrict__ kw,
                                                        const float* __restrict__ ct,
                                                        const float* __restrict__ st_,
                                                        u16* __restrict__ Qo,
                                                        u16* __restrict__ Ko) {
  int wid = blockIdx.x * 4 + (threadIdx.x >> 6);
  int l = threadIdx.x & 63;
  int row = wid / 20;
  int j = wid - row * 20;
  int b = row >> 11, s = row & 2047;
  bool isq = j < 16;
  int h = isq ? j : (j - 16);
  const u16* src = qkv + (size_t)row * QKV_N + (isq ? h * DH : (2048 + h * DH));
  float x1 = bf2f(src[l]), x2 = bf2f(src[l + 64]);
  float ss = x1 * x1 + x2 * x2;
#pragma unroll
  for (int off = 32; off > 0; off >>= 1) ss += __shfl_xor(ss, off);
  float rn = rsqrtf(ss * (1.0f / 128.0f) + 1e-6f);
  const float* wv = isq ? qw : kw;
  float n1 = x1 * rn * wv[l], n2 = x2 * rn * wv[l + 64];
  float cv = ct[s * 64 + l], sv = st_[s * 64 + l];
  float o1 = n1 * cv - n2 * sv;
  float o2 = n2 * cv + n1 * sv;
  float scale = isq ? 0.08838834764831845f : 1.0f;   // 1/sqrt(128) folded into Q
  u16* dst = isq ? (Qo + ((size_t)(b * NH + h) * S_LEN + s) * DH)
                 : (Ko + ((size_t)(b * NKV + h) * S_LEN + s) * DH);
  dst[l]      = f2bf(o1 * scale);
  dst[l + 64] = f2bf(o2 * scale);
}

// ------------- V transpose: qkv[...,2560+h*128+d] -> vt[(b*4+h)*128+d][S] -------------
__global__ void __launch_bounds__(256) vtrans_kernel(const u16* __restrict__ qkv,
                                                     u16* __restrict__ vt) {
  __shared__ u16 t[64][65];
  const int st = blockIdx.x, dt = blockIdx.y, bz = blockIdx.z;  // bz = b*4+h
  const int tid = threadIdx.x;
#pragma unroll
  for (int rep = 0; rep < 16; ++rep) {
    int lin = rep * 256 + tid;
    int i = lin >> 6, jj = lin & 63;                // i = s-local, jj = d-local
    t[i][jj] = qkv[(size_t)((bz >> 2) * S_LEN + st * 64 + i) * QKV_N
                   + 2560 + (bz & 3) * DH + dt * 64 + jj];
  }
  __syncthreads();
#pragma unroll
  for (int rep = 0; rep < 16; ++rep) {
    int lin = rep * 256 + tid;
    int dr = lin >> 6, sc = lin & 63;
    vt[((size_t)bz * DH + dt * 64 + dr) * S_LEN + st * 64 + sc] = t[sc][dr];
  }
}

// ------------- flash attention: 128 q-rows/block, 4 waves x TWO 16-row q-blocks each -------------
// Each K/V fragment read from LDS feeds TWO MFMAs (q-blocks share kv operands) -> LDS-pipe
// traffic per tile halves vs 8-wave R6 (which was ~57% LDS-busy). K+V dbuf 64KB, 1 barrier/iter.
// Defer-max (T13), cvtpk (T12), setprio (T5). Block id: bits [2:0]=(b,kvh) XCD-affine,
// bits [4:3]=q-head in kv group, bits [8:5]=LPT q-tile (longest first).
__global__ void __launch_bounds__(256, 2) attn_kernel(const u16* __restrict__ Qg,
                                                      const u16* __restrict__ Kg,
                                                      const u16* __restrict__ Vt,
                                                      u16* __restrict__ O) {
  __shared__ __align__(16) char smem[65536];   // [2][ K:16KB | V:16KB ]
  const int tid = threadIdx.x;
  const int w = tid >> 6, l = tid & 63;        // w = 0..3
  const int g = l >> 4, q15 = l & 15;
  const int id = blockIdx.x;
  const int grp = id & 7;                      // b*4 + kvh
  const int mem = (id >> 3) & 3;               // q-head within kv group
  const int tq  = 15 - (id >> 5);              // LPT: longest first
  const int b   = grp >> 2, kvh = grp & 3;
  const int h   = kvh * 4 + mem;
  const int qb  = tq * 128;
  const int nkt = 2 * tq + 1;                  // last kv tile index

  // Two q-blocks per wave: rows qb + w*32 + p*16 + q15 (p = 0,1)
  bf16x8 qreg[2][4];
#pragma unroll
  for (int p = 0; p < 2; ++p) {
    const u16* Qrow = Qg + ((size_t)(b * NH + h) * S_LEN + qb + w * 32 + p * 16 + q15) * DH;
#pragma unroll
    for (int c = 0; c < 4; ++c)
      qreg[p][c] = *(const bf16x8*)(Qrow + c * 32 + g * 8);
  }

  const char* Kbase = (const char*)(Kg + (size_t)(b * NKV + kvh) * S_LEN * DH);
  const char* Vbase = (const char*)(Vt + (size_t)(b * NKV + kvh) * DH * S_LEN);

  // stage KV tile kt into buffer `buf`: each of the 4 waves stages 4KB of K + 4KB of V.
  // Linear LDS dest + XOR-pre-swizzled global source (rule 21).
  auto stage = [&](int buf, int kt) {
    char* Ksb = smem + buf * 32768;
    char* Vsb = Ksb + 16384;
    const char* Kt  = Kbase + (size_t)kt * 64 * 256;
    const char* Vtb = Vbase + (size_t)kt * 128;
#pragma unroll
    for (int i = 0; i < 4; ++i) {
      int off = w * 4096 + i * 1024 + l * 16;
      { int row = off >> 8; int cb = (off & 255) ^ ((row & 7) << 4);
        gload_lds16(Kt + (size_t)row * 256 + cb, Ksb + off); }
      { int row = off >> 7; int cb = (off & 127) ^ ((row & 7) << 4);
        gload_lds16(Vtb + (size_t)row * (S_LEN * 2) + cb, Vsb + off); }
    }
  };

  const f32x4 fz = {0.f, 0.f, 0.f, 0.f};
  f32x4 acc[2][8];
#pragma unroll
  for (int p = 0; p < 2; ++p)
#pragma unroll
    for (int n = 0; n < 8; ++n) acc[p][n] = fz;
  float mrun[2] = {-1e30f, -1e30f}, lrun[2] = {0.f, 0.f};

  stage(0, 0);
  __syncthreads();
  int cur = 0;

  for (int kt = 0; kt <= nkt; ++kt) {
    if (kt < nkt) stage(cur ^ 1, kt + 1);     // prefetch next tile (overlaps compute)
    const char* Ks = smem + cur * 32768;
    const char* Vs = Ks + 16384;

    // QK^T swapped: each kf feeds both q-blocks. lane: q=l&15, kv=stt*16+4g+r
    f32x4 sa[2][4];
#pragma unroll
    for (int p = 0; p < 2; ++p)
#pragma unroll
      for (int stt = 0; stt < 4; ++stt) sa[p][stt] = fz;
    __builtin_amdgcn_s_setprio(1);
#pragma unroll
    for (int stt = 0; stt < 4; ++stt) {
      int krow = stt * 16 + q15;
      const char* kr = Ks + krow * 256;
      int sw = (krow & 7) << 4;
#pragma unroll
      for (int c = 0; c < 4; ++c) {
        bf16x8 kf = *(const bf16x8*)(kr + ((c * 64 + g * 16) ^ sw));
        sa[0][stt] = __builtin_amdgcn_mfma_f32_16x16x32_bf16(kf, qreg[0][c], sa[0][stt], 0, 0, 0);
        sa[1][stt] = __builtin_amdgcn_mfma_f32_16x16x32_bf16(kf, qreg[1][c], sa[1][stt], 0, 0, 0);
      }
    }
    __builtin_amdgcn_s_setprio(0);

    // online softmax per q-block (scale pre-folded into Q), defer-max (T13)
    float tmax[2] = {-1e30f, -1e30f};
#pragma unroll
    for (int p = 0; p < 2; ++p) {
      const bool domask = (kt * 64 + 63) > (qb + w * 32 + p * 16);
#pragma unroll
      for (int stt = 0; stt < 4; ++stt)
#pragma unroll
        for (int r = 0; r < 4; ++r) {
          float v = sa[p][stt][r];
          if (domask) {
            int kvg = kt * 64 + stt * 16 + g * 4 + r;
            int qg  = qb + w * 32 + p * 16 + q15;
            if (kvg > qg) v = -1e30f;
          }
          sa[p][stt][r] = v;
          tmax[p] = fmaxf(tmax[p], v);
        }
      tmax[p] = fmaxf(tmax[p], __shfl_xor(tmax[p], 16));
      tmax[p] = fmaxf(tmax[p], __shfl_xor(tmax[p], 32));
    }

    const bool defer = __all(tmax[0] <= mrun[0] + 8.0f && tmax[1] <= mrun[1] + 8.0f);

    u32 pk[2][4][2];
#pragma unroll
    for (int p = 0; p < 2; ++p) {
      float mnew = defer ? mrun[p] : fmaxf(mrun[p], tmax[p]);
      float tsum = 0.f;
#pragma unroll
      for (int stt = 0; stt < 4; ++stt) {
        float p0 = __expf(sa[p][stt][0] - mnew);
        float p1 = __expf(sa[p][stt][1] - mnew);
        float p2 = __expf(sa[p][stt][2] - mnew);
        float p3 = __expf(sa[p][stt][3] - mnew);
        tsum += p0 + p1 + p2 + p3;
        pk[p][stt][0] = cvtpk(p0, p1);
        pk[p][stt][1] = cvtpk(p2, p3);
      }
      tsum += __shfl_xor(tsum, 16);
      tsum += __shfl_xor(tsum, 32);
      if (defer) {
        lrun[p] += tsum;
      } else {
        float alpha = __expf(mrun[p] - mnew);
        lrun[p] = lrun[p] * alpha + tsum;
        mrun[p] = mnew;
        float af4[4];
#pragma unroll
        for (int r = 0; r < 4; ++r) af4[r] = __shfl(alpha, g * 4 + r);
#pragma unroll
        for (int n = 0; n < 8; ++n) {
          f32x4 t = acc[p][n];
          t[0] *= af4[0]; t[1] *= af4[1]; t[2] *= af4[2]; t[3] *= af4[3];
          acc[p][n] = t;
        }
      }
    }

    // PV: redistribute P^T into A-frags (per q-block); each bv read feeds both q-blocks
#pragma unroll
    for (int c = 0; c < 2; ++c) {
      int srcA = ((2 * (g & 1)) << 4) | q15;
      int srcB = srcA + 16;
      union { u32 u[4]; bf16x8 v; } afr[2];
#pragma unroll
      for (int p = 0; p < 2; ++p) {
        u32 a00 = __shfl(pk[p][2 * c][0], srcA),     a01 = __shfl(pk[p][2 * c][1], srcA);
        u32 a02 = __shfl(pk[p][2 * c][0], srcB),     a03 = __shfl(pk[p][2 * c][1], srcB);
        u32 a10 = __shfl(pk[p][2 * c + 1][0], srcA), a11 = __shfl(pk[p][2 * c + 1][1], srcA);
        u32 a12 = __shfl(pk[p][2 * c + 1][0], srcB), a13 = __shfl(pk[p][2 * c + 1][1], srcB);
        bool hi = (g & 2) != 0;
        afr[p].u[0] = hi ? a10 : a00;
        afr[p].u[1] = hi ? a11 : a01;
        afr[p].u[2] = hi ? a12 : a02;
        afr[p].u[3] = hi ? a13 : a03;
      }
      __builtin_amdgcn_s_setprio(1);
#pragma unroll
      for (int n = 0; n < 8; ++n) {
        int d = n * 16 + q15;
        const char* vr = Vs + d * 128;
        int sw = (d & 7) << 4;
        bf16x8 bv = *(const bf16x8*)(vr + ((c * 64 + g * 16) ^ sw));
        acc[0][n] = __builtin_amdgcn_mfma_f32_16x16x32_bf16(afr[0].v, bv, acc[0][n], 0, 0, 0);
        acc[1][n] = __builtin_amdgcn_mfma_f32_16x16x32_bf16(afr[1].v, bv, acc[1][n], 0, 0, 0);
      }
      __builtin_amdgcn_s_setprio(0);
    }
    __syncthreads();   // drains prefetch (vmcnt 0) + guards buffer reuse
    cur ^= 1;
  }

  // epilogue: divide by l, store bf16 to [b][s][h*128+d]
#pragma unroll
  for (int p = 0; p < 2; ++p) {
    float linv[4];
#pragma unroll
    for (int r = 0; r < 4; ++r) linv[r] = 1.0f / __shfl(lrun[p], g * 4 + r);
#pragma unroll
    for (int n = 0; n < 8; ++n)
#pragma unroll
      for (int r = 0; r < 4; ++r) {
        size_t orow = (size_t)b * S_LEN + qb + w * 32 + p * 16 + g * 4 + r;
        O[orow * DM + h * DH + n * 16 + q15] = f2bf(acc[p][n][r] * linv[r]);
      }
  }
}

extern "C" void kernel_launch(void* const* d_in, const int* in_sizes, int n_in,
                              void* d_out, int out_size, void* d_ws, size_t ws_size,
                              hipStream_t stream) {
  (void)in_sizes; (void)n_in; (void)out_size; (void)ws_size;
  const float* x  = (const float*)d_in[0];
  const float* Wq = (const float*)d_in[1];
  const float* Wk = (const float*)d_in[2];
  const float* Wv = (const float*)d_in[3];
  const float* Wo = (const float*)d_in[4];
  const float* qw = (const float*)d_in[5];
  const float* kw = (const float*)d_in[6];

  char* ws = (char*)d_ws;
  // ws layout (~61 MB). attn_out aliases xb (xb dead after gemm1).
  u16*   xb    = (u16*)(ws + 0);                       // 16.8 MB [4096][2048]
  u16*   wqkvt = (u16*)(ws + 16777216);                // 12.6 MB [3072][2048]
  u16*   wot   = (u16*)(ws + 29360128);                //  8.4 MB [2048][2048]
  u16*   qo    = (u16*)(ws + 37748736);                // 16.8 MB [B][16][S][128]
  u16*   ko    = (u16*)(ws + 54525952);                //  4.2 MB [B][4][S][128]
  u16*   vt    = (u16*)(ws + 58720256);                //  4.2 MB [B][4][128][S]
  float* ctab  = (float*)(ws + 62914560);              //  0.5 MB
  float* stab  = (float*)(ws + 63438848);              //  0.5 MB
  u16*   qkvp  = (u16*)d_out;                          // 25.2 MB staged in d_out
  u16*   attn  = (u16*)(ws + 0);                       // aliases xb
  float* outp  = (float*)d_out;

  convert_x_kernel<<<4096, 256, 0, stream>>>(x, xb);
  transpose_w_kernel<<<dim3(32, 32), 256, 0, stream>>>(Wq, wqkvt, 2048);
  transpose_w_kernel<<<dim3(32, 8),  256, 0, stream>>>(Wk, wqkvt + (size_t)2048 * 2048, 512);
  transpose_w_kernel<<<dim3(32, 8),  256, 0, stream>>>(Wv, wqkvt + (size_t)2560 * 2048, 512);
  transpose_w_kernel<<<dim3(32, 32), 256, 0, stream>>>(Wo, wot, 2048);
  rope_tables_kernel<<<512, 256, 0, stream>>>(ctab, stab);

  gemm_bt<0><<<dim3(24, 32), 256, 0, stream>>>(xb, wqkvt, qkvp, MROWS, QKV_N, DM);
  norm_rope_kernel<<<20480, 256, 0, stream>>>(qkvp, qw, kw, ctab, stab, qo, ko);
  vtrans_kernel<<<dim3(32, 2, 8), 256, 0, stream>>>(qkvp, vt);
  attn_kernel<<<512, 256, 0, stream>>>(qo, ko, vt, attn);
  gemm_bt<1><<<dim3(16, 32), 256, 0, stream>>>(attn, wot, outp, MROWS, DM, DM);
}

// Round 9
// 240.083 us; speedup vs baseline: 1.0876x; 1.0876x over previous
//
#include <hip/hip_runtime.h>
#include <stdint.h>

typedef __attribute__((ext_vector_type(8))) short bf16x8;
typedef __attribute__((ext_vector_type(4))) float f32x4;
typedef __attribute__((ext_vector_type(16))) float f32x16;
typedef unsigned short u16;
typedef unsigned int   u32;
typedef unsigned long long u64;

#define S_LEN 2048
#define NH    16
#define NKV   4
#define DH    128
#define DM    2048
#define QKV_N 3072
#define MROWS 4096   // B*S

__device__ __forceinline__ u16 f2bf(float x) {
  u32 u = __float_as_uint(x);
  return (u16)((u + 0x7fffu + ((u >> 16) & 1u)) >> 16);   // RNE
}
__device__ __forceinline__ float bf2f(u16 h) {
  return __uint_as_float(((u32)h) << 16);
}
__device__ __forceinline__ u32 cvtpk(float lo, float hi) {   // T12: 1 instr vs ~8 VALU
  u32 r;
  asm("v_cvt_pk_bf16_f32 %0, %1, %2" : "=v"(r) : "v"(lo), "v"(hi));
  return r;
}
__device__ __forceinline__ void plswap(u32& a, u32& b) {     // dst.hi32lanes <-> src.lo32lanes
  asm volatile("v_permlane32_swap_b32 %0, %1" : "+v"(a), "+v"(b));
}
__device__ __forceinline__ void gload_lds16(const void* g, void* l) {
  __builtin_amdgcn_global_load_lds((const __attribute__((address_space(1))) void*)g,
                                   (__attribute__((address_space(3))) void*)l, 16, 0, 0);
}

// ---------------- f32 -> bf16 convert (vectorized, G13) ----------------
__global__ void __launch_bounds__(256) convert_x_kernel(const float* __restrict__ x,
                                                        u16* __restrict__ o) {
  int idx = (blockIdx.x * 256 + threadIdx.x) * 8;
  float4 a = *(const float4*)(x + idx);
  float4 b = *(const float4*)(x + idx + 4);
  union { u16 s[8]; uint4 v; } t;
  t.s[0] = f2bf(a.x); t.s[1] = f2bf(a.y); t.s[2] = f2bf(a.z); t.s[3] = f2bf(a.w);
  t.s[4] = f2bf(b.x); t.s[5] = f2bf(b.y); t.s[6] = f2bf(b.z); t.s[7] = f2bf(b.w);
  *(uint4*)(o + idx) = t.v;
}

// ------------- W [2048][N] f32  ->  Wt [N][2048] bf16 (LDS tiled) -------------
__global__ void __launch_bounds__(256) transpose_w_kernel(const float* __restrict__ src,
                                                          u16* __restrict__ dst, int N) {
  __shared__ float t[64][65];
  const int bx = blockIdx.x, by = blockIdx.y, tid = threadIdx.x;
#pragma unroll
  for (int rep = 0; rep < 16; ++rep) {
    int lin = rep * 256 + tid;
    int i = lin >> 6, jj = lin & 63;                 // i = k-local, jj = n-local
    t[i][jj] = src[(size_t)(bx * 64 + i) * N + by * 64 + jj];
  }
  __syncthreads();
#pragma unroll
  for (int rep = 0; rep < 16; ++rep) {
    int lin = rep * 256 + tid;
    int nr = lin >> 6, kc = lin & 63;
    dst[(size_t)(by * 64 + nr) * DM + bx * 64 + kc] = f2bf(t[kc][nr]);
  }
}

// ------------- RoPE tables: ctab/stab[s*64 + i] -------------
__global__ void __launch_bounds__(256) rope_tables_kernel(float* __restrict__ ct,
                                                          float* __restrict__ st_) {
  int idx = blockIdx.x * 256 + threadIdx.x;          // 2048*64
  int s = idx >> 6, i = idx & 63;
  const float L2_10000 = 13.287712379549449f;
  float freq = exp2f(-(float)i * (1.0f / 64.0f) * L2_10000);
  float ang = (float)s * freq;
  ct[idx] = cosf(ang);
  st_[idx] = sinf(ang);
}

// ------------- GEMM: C[M][N] = A[M][K](bf16) * Bt[N][K](bf16)^T  (m97 structure) -------------
template <int OUTF32>
__global__ void __launch_bounds__(256) gemm_bt(const u16* __restrict__ A,
                                               const u16* __restrict__ Bt,
                                               void* __restrict__ C,
                                               int M, int N, int K) {
  __shared__ __align__(16) u16 As[128 * 32];
  __shared__ __align__(16) u16 Bs[128 * 32];
  const int tid = threadIdx.x;
  const int w = tid >> 6, l = tid & 63;
  const int g = l >> 4, q15 = l & 15;
  const int row0 = blockIdx.y * 128, col0 = blockIdx.x * 128;
  const int wm = (w >> 1) * 64, wn = (w & 1) * 64;
  const f32x4 fz = {0.f, 0.f, 0.f, 0.f};
  f32x4 acc[4][4];
#pragma unroll
  for (int m = 0; m < 4; ++m)
#pragma unroll
    for (int n = 0; n < 4; ++n) acc[m][n] = fz;

  for (int kt = 0; kt < K; kt += 32) {
#pragma unroll
    for (int c = 0; c < 2; ++c) {
      int P = (w * 2 + c) * 1024;
      int Pl = P + l * 16;
      int arow = Pl >> 6, acolb = Pl & 63;          // 64B per 32-elem row
      gload_lds16((const char*)A + ((size_t)(row0 + arow) * K + kt) * 2 + acolb,
                  (char*)As + P);
      gload_lds16((const char*)Bt + ((size_t)(col0 + arow) * K + kt) * 2 + acolb,
                  (char*)Bs + P);
    }
    __syncthreads();
    bf16x8 af[4], bfv[4];
#pragma unroll
    for (int m = 0; m < 4; ++m)
      af[m] = *(const bf16x8*)((const char*)As + (wm + m * 16 + q15) * 64 + g * 16);
#pragma unroll
    for (int n = 0; n < 4; ++n)
      bfv[n] = *(const bf16x8*)((const char*)Bs + (wn + n * 16 + q15) * 64 + g * 16);
#pragma unroll
    for (int m = 0; m < 4; ++m)
#pragma unroll
      for (int n = 0; n < 4; ++n)
        acc[m][n] = __builtin_amdgcn_mfma_f32_16x16x32_bf16(af[m], bfv[n], acc[m][n], 0, 0, 0);
    __syncthreads();
  }
#pragma unroll
  for (int m = 0; m < 4; ++m)
#pragma unroll
    for (int n = 0; n < 4; ++n)
#pragma unroll
      for (int r = 0; r < 4; ++r) {
        int rr = row0 + wm + m * 16 + g * 4 + r;    // C/D: row=(l>>4)*4+reg
        int cc = col0 + wn + n * 16 + q15;          //      col=l&15
        float v = acc[m][n][r];
        if (OUTF32) ((float*)C)[(size_t)rr * N + cc] = v;
        else        ((u16*)C)[(size_t)rr * N + cc]  = f2bf(v);
      }
}

// ------------- fused RMSNorm + RoPE; one wave per (row, head-job) -------------
// jobs 0..15 = q heads (pre-scaled by 1/sqrt(DH)), 16..19 = k heads
__global__ void __launch_bounds__(256) norm_rope_kernel(const u16* __restrict__ qkv,
                                                        const float* __restrict__ qw,
                                                        const float* __restrict__ kw,
                                                        const float* __restrict__ ct,
                                                        const float* __restrict__ st_,
                                                        u16* __restrict__ Qo,
                                                        u16* __restrict__ Ko) {
  int wid = blockIdx.x * 4 + (threadIdx.x >> 6);
  int l = threadIdx.x & 63;
  int row = wid / 20;
  int j = wid - row * 20;
  int b = row >> 11, s = row & 2047;
  bool isq = j < 16;
  int h = isq ? j : (j - 16);
  const u16* src = qkv + (size_t)row * QKV_N + (isq ? h * DH : (2048 + h * DH));
  float x1 = bf2f(src[l]), x2 = bf2f(src[l + 64]);
  float ss = x1 * x1 + x2 * x2;
#pragma unroll
  for (int off = 32; off > 0; off >>= 1) ss += __shfl_xor(ss, off);
  float rn = rsqrtf(ss * (1.0f / 128.0f) + 1e-6f);
  const float* wv = isq ? qw : kw;
  float n1 = x1 * rn * wv[l], n2 = x2 * rn * wv[l + 64];
  float cv = ct[s * 64 + l], sv = st_[s * 64 + l];
  float o1 = n1 * cv - n2 * sv;
  float o2 = n2 * cv + n1 * sv;
  float scale = isq ? 0.08838834764831845f : 1.0f;   // 1/sqrt(128) folded into Q
  u16* dst = isq ? (Qo + ((size_t)(b * NH + h) * S_LEN + s) * DH)
                 : (Ko + ((size_t)(b * NKV + h) * S_LEN + s) * DH);
  dst[l]      = f2bf(o1 * scale);
  dst[l + 64] = f2bf(o2 * scale);
}

// ------------- V transpose: qkv[...,2560+h*128+d] -> vt[(b*4+h)*128+d][S] -------------
__global__ void __launch_bounds__(256) vtrans_kernel(const u16* __restrict__ qkv,
                                                     u16* __restrict__ vt) {
  __shared__ u16 t[64][65];
  const int st = blockIdx.x, dt = blockIdx.y, bz = blockIdx.z;  // bz = b*4+h
  const int tid = threadIdx.x;
#pragma unroll
  for (int rep = 0; rep < 16; ++rep) {
    int lin = rep * 256 + tid;
    int i = lin >> 6, jj = lin & 63;                // i = s-local, jj = d-local
    t[i][jj] = qkv[(size_t)((bz >> 2) * S_LEN + st * 64 + i) * QKV_N
                   + 2560 + (bz & 3) * DH + dt * 64 + jj];
  }
  __syncthreads();
#pragma unroll
  for (int rep = 0; rep < 16; ++rep) {
    int lin = rep * 256 + tid;
    int dr = lin >> 6, sc = lin & 63;
    vt[((size_t)bz * DH + dt * 64 + dr) * S_LEN + st * 64 + sc] = t[sc][dr];
  }
}

// ------------- flash attention, 32x32 swapped-QK core (m214 structure) -------------
// 128 q-rows/block, 4 warps x 32 q-rows, KV tile 64. K+V dbuf in LDS (64KB).
// QK^T = mfma_32x32x16(K,Q): lane holds P[q=l&31][16 kv-rows] -> softmax reduce is
// in-lane + ONE shfl_xor(32). P -> PV B-frag via 16 cvt_pk + 8 permlane32_swap (VALU only).
// PV computes O^T = mfma(V^T, P^T): output col = q = l&31 -> alpha-rescale and 1/l epilogue
// are lane-local (zero shuffles). Defer-max (T13), setprio (T5).
// Swizzles (both-sides, rule 21): K rows 256B, XOR (row&15)<<4; V stored d-paired
// ([64 rows][256B], row=d>>1, half bit = d&1) with XOR (row&15)<<4 over the full byte.
// Block id: bits [2:0]=(b,kvh) XCD-affine, [4:3]=q-head, [8:5]=LPT q-tile (longest first).
__global__ void __launch_bounds__(256, 2) attn_kernel(const u16* __restrict__ Qg,
                                                      const u16* __restrict__ Kg,
                                                      const u16* __restrict__ Vt,
                                                      u16* __restrict__ O) {
  __shared__ __align__(16) char smem[65536];   // [2][ K:16KB | V:16KB ]
  const int tid = threadIdx.x;
  const int w = tid >> 6, l = tid & 63;        // w = 0..3
  const int q31 = l & 31, hi = l >> 5;
  const int id = blockIdx.x;
  const int grp = id & 7;                      // b*4 + kvh
  const int mem = (id >> 3) & 3;               // q-head within kv group
  const int tq  = 15 - (id >> 5);              // LPT: longest first
  const int b   = grp >> 2, kvh = grp & 3;
  const int h   = kvh * 4 + mem;
  const int qb  = tq * 128;
  const int nkt = 2 * tq + 1;                  // last kv tile index
  const int qg  = qb + w * 32 + q31;           // lane's q row

  // Q row in registers: lane l&31 owns row qg; chunk c covers d = c*16 + hi*8 .. +7
  bf16x8 qreg[8];
  const u16* Qrow = Qg + ((size_t)(b * NH + h) * S_LEN + qg) * DH;
#pragma unroll
  for (int c = 0; c < 8; ++c)
    qreg[c] = *(const bf16x8*)(Qrow + c * 16 + hi * 8);

  const char* Kbase = (const char*)(Kg + (size_t)(b * NKV + kvh) * S_LEN * DH);
  const char* Vbase = (const char*)(Vt + (size_t)(b * NKV + kvh) * DH * S_LEN);

  // stage KV tile kt into buffer `buf` (linear LDS dest + inverse-swizzled global src)
  auto stage = [&](int buf, int kt) {
    char* Ksb = smem + buf * 32768;
    char* Vsb = Ksb + 16384;
    const char* Kt  = Kbase + (size_t)kt * 64 * 256;
    const char* Vtb = Vbase + (size_t)kt * 128;
#pragma unroll
    for (int i = 0; i < 4; ++i) {
      int off = w * 4096 + i * 1024 + l * 16;
      int row = off >> 8;
      { // K: [64 kv][128 d] bf16, rows 256B, XOR (row&15)<<4
        int cb = (off & 255) ^ ((row & 15) << 4);
        gload_lds16(Kt + (size_t)row * 256 + cb, Ksb + off); }
      { // V: d-paired rows: row=d>>1, byte7=d&1, low 7 bits = kv*2
        int qoff = (off & 255) ^ ((row & 15) << 4);
        int d = row * 2 + (qoff >> 7);
        int kvb = qoff & 127;
        gload_lds16(Vtb + (size_t)d * (S_LEN * 2) + kvb, Vsb + off); }
    }
  };

  f32x16 acc[4];
#pragma unroll
  for (int dt = 0; dt < 4; ++dt)
#pragma unroll
    for (int r = 0; r < 16; ++r) acc[dt][r] = 0.f;
  float mrun = -1e30f, lrun = 0.f;

  stage(0, 0);
  __syncthreads();
  int cur = 0;

  for (int kt = 0; kt <= nkt; ++kt) {
    if (kt < nkt) stage(cur ^ 1, kt + 1);     // prefetch next tile (overlaps compute)
    const char* Ks = smem + cur * 32768;
    const char* Vs = Ks + 16384;

    // QK^T swapped: sa[s] = K[s-subtile] * Q^T -> P^T tile [32 kv][32 q]
    // lane: q=l&31; reg r -> kv = s*32 + (r&3) + 8*(r>>2) + 4*hi
    f32x16 sa[2];
#pragma unroll
    for (int s = 0; s < 2; ++s)
#pragma unroll
      for (int r = 0; r < 16; ++r) sa[s][r] = 0.f;
    __builtin_amdgcn_s_setprio(1);
#pragma unroll
    for (int s = 0; s < 2; ++s) {
      int krow = s * 32 + q31;
      const char* kr = Ks + krow * 256;
      int sw = (krow & 15) << 4;
#pragma unroll
      for (int c = 0; c < 8; ++c) {
        bf16x8 kf = *(const bf16x8*)(kr + ((c * 32 + hi * 16) ^ sw));
        sa[s] = __builtin_amdgcn_mfma_f32_32x32x16_bf16(kf, qreg[c], sa[s], 0, 0, 0);
      }
    }
    __builtin_amdgcn_s_setprio(0);

    // masking + in-lane max. FIX (R8 bug): bound is kt*64+63 vs warp base (was +32,
    // which left the upper-half warps' diagonal tiles unmasked).
    const bool domask = (kt * 64 + 63) > (qb + w * 32);
    float tmax = -1e30f;
#pragma unroll
    for (int s = 0; s < 2; ++s)
#pragma unroll
      for (int r = 0; r < 16; ++r) {
        float v = sa[s][r];
        if (domask) {
          int kvg = kt * 64 + s * 32 + (r & 3) + 8 * (r >> 2) + 4 * hi;
          if (kvg > qg) v = -1e30f;
        }
        sa[s][r] = v;
        tmax = fmaxf(tmax, v);
      }
    tmax = fmaxf(tmax, __shfl_xor(tmax, 32));

    const bool defer = __all(tmax <= mrun + 8.0f);  // T13 (wave-uniform)
    const float mnew = defer ? mrun : fmaxf(mrun, tmax);

    // exp + pack to PV B-frags: pfrag[ks] = P[q=l&31][kv = ks*16 + hi*8 + (0..7)]
    float tsum = 0.f;
    union { u32 u[4]; bf16x8 v; } pf[4];
#pragma unroll
    for (int s = 0; s < 2; ++s)
#pragma unroll
      for (int kl = 0; kl < 2; ++kl) {
        float e0 = __expf(sa[s][kl * 8 + 0] - mnew);
        float e1 = __expf(sa[s][kl * 8 + 1] - mnew);
        float e2 = __expf(sa[s][kl * 8 + 2] - mnew);
        float e3 = __expf(sa[s][kl * 8 + 3] - mnew);
        float e4 = __expf(sa[s][kl * 8 + 4] - mnew);
        float e5 = __expf(sa[s][kl * 8 + 5] - mnew);
        float e6 = __expf(sa[s][kl * 8 + 6] - mnew);
        float e7 = __expf(sa[s][kl * 8 + 7] - mnew);
        tsum += (e0 + e1) + (e2 + e3) + (e4 + e5) + (e6 + e7);
        u32 A0 = cvtpk(e0, e1), A1 = cvtpk(e2, e3);
        u32 B0 = cvtpk(e4, e5), B1 = cvtpk(e6, e7);
        plswap(A0, B0);   // -> A0 = word0 (kv +0,1 | +8,9), B0 = word2 (kv +4,5 | +12,13)
        plswap(A1, B1);   // -> A1 = word1,          B1 = word3
        int ks = s * 2 + kl;
        pf[ks].u[0] = A0; pf[ks].u[1] = A1; pf[ks].u[2] = B0; pf[ks].u[3] = B1;
      }
    tsum += __shfl_xor(tsum, 32);

    if (defer) {
      lrun += tsum;
    } else {
      float alpha = __expf(mrun - mnew);
      lrun = lrun * alpha + tsum;
      mrun = mnew;
#pragma unroll
      for (int dt = 0; dt < 4; ++dt)
#pragma unroll
        for (int r = 0; r < 16; ++r) acc[dt][r] *= alpha;   // lane-local (col = q)
    }

    // PV: acc[dt] += V^T-frag(dt,ks) * pfrag[ks]  -> O^T[d][q]
    __builtin_amdgcn_s_setprio(1);
#pragma unroll
    for (int dt = 0; dt < 4; ++dt) {
      int d = dt * 32 + q31;
      int vrow = d >> 1;
      const char* vr = Vs + vrow * 256;
      int sw = (vrow & 15) << 4;
      int hb = (d & 1) << 7;
#pragma unroll
      for (int ks = 0; ks < 4; ++ks) {
        bf16x8 vf = *(const bf16x8*)(vr + ((hb | (ks * 32 + hi * 16)) ^ sw));
        acc[dt] = __builtin_amdgcn_mfma_f32_32x32x16_bf16(vf, pf[ks].v, acc[dt], 0, 0, 0);
      }
    }
    __builtin_amdgcn_s_setprio(0);

    __syncthreads();   // drains prefetch (vmcnt 0) + guards buffer reuse
    cur ^= 1;
  }

  // epilogue: lane-local 1/l, pack pairs, 8B stores. acc[dt][r] = O[qg][dt*32+(r&3)+8*(r>>2)+4*hi]
  const float linv = 1.0f / lrun;
  u16* Obase = O + ((size_t)b * S_LEN + qg) * DM + h * DH;
#pragma unroll
  for (int dt = 0; dt < 4; ++dt)
#pragma unroll
    for (int rg = 0; rg < 4; ++rg) {
      int d0 = dt * 32 + rg * 8 + hi * 4;
      u32 w0 = cvtpk(acc[dt][rg * 4 + 0] * linv, acc[dt][rg * 4 + 1] * linv);
      u32 w1 = cvtpk(acc[dt][rg * 4 + 2] * linv, acc[dt][rg * 4 + 3] * linv);
      u64 vv = (u64)w0 | ((u64)w1 << 32);
      *(u64*)(Obase + d0) = vv;
    }
}

extern "C" void kernel_launch(void* const* d_in, const int* in_sizes, int n_in,
                              void* d_out, int out_size, void* d_ws, size_t ws_size,
                              hipStream_t stream) {
  (void)in_sizes; (void)n_in; (void)out_size; (void)ws_size;
  const float* x  = (const float*)d_in[0];
  const float* Wq = (const float*)d_in[1];
  const float* Wk = (const float*)d_in[2];
  const float* Wv = (const float*)d_in[3];
  const float* Wo = (const float*)d_in[4];
  const float* qw = (const float*)d_in[5];
  const float* kw = (const float*)d_in[6];

  char* ws = (char*)d_ws;
  // ws layout (~61 MB). attn_out aliases xb (xb dead after gemm1).
  u16*   xb    = (u16*)(ws + 0);                       // 16.8 MB [4096][2048]
  u16*   wqkvt = (u16*)(ws + 16777216);                // 12.6 MB [3072][2048]
  u16*   wot   = (u16*)(ws + 29360128);                //  8.4 MB [2048][2048]
  u16*   qo    = (u16*)(ws + 37748736);                // 16.8 MB [B][16][S][128]
  u16*   ko    = (u16*)(ws + 54525952);                //  4.2 MB [B][4][S][128]
  u16*   vt    = (u16*)(ws + 58720256);                //  4.2 MB [B][4][128][S]
  float* ctab  = (float*)(ws + 62914560);              //  0.5 MB
  float* stab  = (float*)(ws + 63438848);              //  0.5 MB
  u16*   qkvp  = (u16*)d_out;                          // 25.2 MB staged in d_out
  u16*   attn  = (u16*)(ws + 0);                       // aliases xb
  float* outp  = (float*)d_out;

  convert_x_kernel<<<4096, 256, 0, stream>>>(x, xb);
  transpose_w_kernel<<<dim3(32, 32), 256, 0, stream>>>(Wq, wqkvt, 2048);
  transpose_w_kernel<<<dim3(32, 8),  256, 0, stream>>>(Wk, wqkvt + (size_t)2048 * 2048, 512);
  transpose_w_kernel<<<dim3(32, 8),  256, 0, stream>>>(Wv, wqkvt + (size_t)2560 * 2048, 512);
  transpose_w_kernel<<<dim3(32, 32), 256, 0, stream>>>(Wo, wot, 2048);
  rope_tables_kernel<<<512, 256, 0, stream>>>(ctab, stab);

  gemm_bt<0><<<dim3(24, 32), 256, 0, stream>>>(xb, wqkvt, qkvp, MROWS, QKV_N, DM);
  norm_rope_kernel<<<20480, 256, 0, stream>>>(qkvp, qw, kw, ctab, stab, qo, ko);
  vtrans_kernel<<<dim3(32, 2, 8), 256, 0, stream>>>(qkvp, vt);
  attn_kernel<<<512, 256, 0, stream>>>(qo, ko, vt, attn);
  gemm_bt<1><<<dim3(16, 32), 256, 0, stream>>>(attn, wot, outp, MROWS, DM, DM);
}